// Round 3
// baseline (453.797 us; speedup 1.0000x reference)
//
#include <hip/hip_runtime.h>
#include <hip/hip_bf16.h>

typedef __attribute__((ext_vector_type(4))) float f32x4;
typedef __attribute__((ext_vector_type(8))) short s16x8;
typedef unsigned short u16;
typedef unsigned int u32;

#define MFMA16 __builtin_amdgcn_mfma_f32_16x16x32_bf16

// global_load_lds: LDS dest is wave-uniform base + lane*16 (linear!), global src per-lane.
#define GLL16(g, l)                                                        \
  __builtin_amdgcn_global_load_lds(                                        \
      (const __attribute__((address_space(1))) void*)(g),                  \
      (__attribute__((address_space(3))) void*)(l), 16, 0, 0)

__device__ __forceinline__ u16 f2b(float f) {
  u32 x = __builtin_bit_cast(u32, f);
  u32 r = (x + 0x7fffu + ((x >> 16) & 1u)) >> 16;
  return (u16)r;
}
__device__ __forceinline__ float b2f(u16 u) {
  u32 x = ((u32)u) << 16;
  return __builtin_bit_cast(float, x);
}

// ---------- fp32 -> bf16 elementwise (x) ----------
__global__ __launch_bounds__(256) void k_cvt(const float* __restrict__ in, u16* __restrict__ out) {
  size_t i = ((size_t)blockIdx.x * 256 + threadIdx.x) * 4;
  float4 v = *(const float4*)(in + i);
  ushort4 o; o.x = f2b(v.x); o.y = f2b(v.y); o.z = f2b(v.z); o.w = f2b(v.w);
  *(ushort4*)(out + i) = o;
}

// ---------- transpose + convert: in (R x C) fp32 -> out (C x R) bf16 ----------
__global__ __launch_bounds__(256) void k_tconv(const float* __restrict__ in, u16* __restrict__ out,
                                               int R, int C) {
  __shared__ u16 tile[64][72];
  int c0 = blockIdx.x * 64, r0 = blockIdx.y * 64;
  int t = threadIdx.x;
#pragma unroll
  for (int p = 0; p < 4; ++p) {
    int idx = p * 1024 + t * 4;
    int row = idx >> 6, col = idx & 63;
    float4 v = *(const float4*)&in[(size_t)(r0 + row) * C + c0 + col];
    tile[row][col]     = f2b(v.x);
    tile[row][col + 1] = f2b(v.y);
    tile[row][col + 2] = f2b(v.z);
    tile[row][col + 3] = f2b(v.w);
  }
  __syncthreads();
#pragma unroll
  for (int p = 0; p < 4; ++p) {
    int idx = p * 1024 + t * 4;
    int row = idx >> 6, col = idx & 63;   // row: c-dim, col: r-dim
    ushort4 o;
    o.x = tile[col][row]; o.y = tile[col + 1][row];
    o.z = tile[col + 2][row]; o.w = tile[col + 3][row];
    *(ushort4*)&out[(size_t)(c0 + row) * R + r0 + col] = o;
  }
}

// ---------- bf16 transpose per (b,h): (2048 s x 128 d) -> (128 d x 2048 s) ----------
__global__ __launch_bounds__(256) void k_trv(const u16* __restrict__ v, u16* __restrict__ vt) {
  __shared__ u16 tile[64][72];
  int bh = blockIdx.z;
  int s0 = blockIdx.x * 64, d0 = blockIdx.y * 64;
  const u16* src = v + (size_t)bh * 2048 * 128;
  u16* dst = vt + (size_t)bh * 2048 * 128;
  int t = threadIdx.x;
#pragma unroll
  for (int p = 0; p < 4; ++p) {
    int idx = p * 1024 + t * 4;
    int row = idx >> 6, col = idx & 63;
    ushort4 x = *(const ushort4*)&src[(size_t)(s0 + row) * 128 + d0 + col];
    tile[row][col] = x.x; tile[row][col + 1] = x.y;
    tile[row][col + 2] = x.z; tile[row][col + 3] = x.w;
  }
  __syncthreads();
#pragma unroll
  for (int p = 0; p < 4; ++p) {
    int idx = p * 1024 + t * 4;
    int row = idx >> 6, col = idx & 63;   // row: d-local, col: s-local
    ushort4 o;
    o.x = tile[col][row]; o.y = tile[col + 1][row];
    o.z = tile[col + 2][row]; o.w = tile[col + 3][row];
    *(ushort4*)&dst[(size_t)(d0 + row) * 2048 + s0 + col] = o;
  }
}

// ---------- RoPE trig table ----------
__global__ __launch_bounds__(256) void k_trig(float2* __restrict__ tab) {
  int t = blockIdx.x * 256 + threadIdx.x;      // 2048*64
  int s = t >> 6, i = t & 63;
  float inv = expf(-(float)i * (9.210340371976184f / 64.f)); // ln(10000)
  float a = (float)s * inv;
  float sn, cs;
  sincosf(a, &sn, &cs);
  tab[t] = make_float2(cs, sn);
}

// ---------- RoPE in-place on q (y=0) / k (y=1), (B*H, S, 128) bf16 ----------
__global__ __launch_bounds__(256) void k_rope(u16* __restrict__ q, u16* __restrict__ k,
                                              const float2* __restrict__ tab) {
  u16* ptr = blockIdx.y ? k : q;
  size_t tid = (size_t)blockIdx.x * 256 + threadIdx.x;  // 32*2048*16
  int g = (int)(tid & 15);
  int s = (int)((tid >> 4) & 2047);
  int bh = (int)(tid >> 15);
  size_t base = ((size_t)bh * 2048 + s) * 128 + (size_t)g * 8;
  uint4 dv = *(const uint4*)(ptr + base);
  u16* pu = (u16*)&dv;
  const float2* tb = &tab[s * 64 + g * 4];
#pragma unroll
  for (int j = 0; j < 4; ++j) {
    float xe = b2f(pu[2 * j]), xo = b2f(pu[2 * j + 1]);
    float c = tb[j].x, sn = tb[j].y;
    pu[2 * j]     = f2b(xe * c - xo * sn);
    pu[2 * j + 1] = f2b(xe * sn + xo * c);
  }
  *(uint4*)(ptr + base) = dv;
}

// ---------- GEMM1 (m97 structure): qkv = xb @ WqkvT^T, scatter into q/k/v (B,H,S,128) ----------
__global__ __launch_bounds__(256) void k_gemm_qkv(const u16* __restrict__ A, const u16* __restrict__ Bt,
                                                  u16* __restrict__ qo, u16* __restrict__ ko,
                                                  u16* __restrict__ vo) {
  constexpr int K = 2048;
  __shared__ u16 sa[128][32];   // linear — required by global_load_lds
  __shared__ u16 sb[128][32];
  int n0 = blockIdx.x * 128;
  int m0 = blockIdx.y * 128;
  int t = threadIdx.x;
  int lane = t & 63, w = t >> 6;
  int wm = (w >> 1) * 64, wn = (w & 1) * 64;
  int lr = lane & 15, lg = lane >> 4;
  int srow0 = w * 32 + (lane >> 2);       // slot 2w
  int srow1 = srow0 + 16;                 // slot 2w+1
  int scol = (lane & 3) * 8;
  const u16* gA0 = &A[(size_t)(m0 + srow0) * K + scol];
  const u16* gA1 = &A[(size_t)(m0 + srow1) * K + scol];
  const u16* gB0 = &Bt[(size_t)(n0 + srow0) * K + scol];
  const u16* gB1 = &Bt[(size_t)(n0 + srow1) * K + scol];
  u16* lA0 = &sa[srow0][scol];
  u16* lA1 = &sa[srow1][scol];
  u16* lB0 = &sb[srow0][scol];
  u16* lB1 = &sb[srow1][scol];
  f32x4 acc[4][4] = {};
  for (int k0 = 0; k0 < K; k0 += 32) {
    __syncthreads();
    GLL16(gA0 + k0, lA0); GLL16(gA1 + k0, lA1);
    GLL16(gB0 + k0, lB0); GLL16(gB1 + k0, lB1);
    __syncthreads();
    s16x8 af[4], bf[4];
#pragma unroll
    for (int i = 0; i < 4; ++i) af[i] = *(const s16x8*)&sa[wm + i * 16 + lr][lg * 8];
#pragma unroll
    for (int i = 0; i < 4; ++i) bf[i] = *(const s16x8*)&sb[wn + i * 16 + lr][lg * 8];
#pragma unroll
    for (int mi = 0; mi < 4; ++mi)
#pragma unroll
      for (int ni = 0; ni < 4; ++ni)
        acc[mi][ni] = MFMA16(af[mi], bf[ni], acc[mi][ni], 0, 0, 0);
  }
  int which = blockIdx.x >> 4;
  int h = blockIdx.x & 15;
  u16* dst = which == 0 ? qo : (which == 1 ? ko : vo);
#pragma unroll
  for (int mi = 0; mi < 4; ++mi)
#pragma unroll
    for (int ni = 0; ni < 4; ++ni)
#pragma unroll
      for (int r = 0; r < 4; ++r) {
        int m = m0 + wm + mi * 16 + lg * 4 + r;
        int d = wn + ni * 16 + lr;
        int b = m >> 11, s = m & 2047;
        dst[(((size_t)b * 16 + h) * 2048 + s) * 128 + d] = f2b(acc[mi][ni][r]);
      }
}

// ---------- GEMM2 (m97 structure): out(fp32) = y(bf16) @ WoT^T ----------
__global__ __launch_bounds__(256) void k_gemm_out(const u16* __restrict__ A, const u16* __restrict__ Bt,
                                                  float* __restrict__ C) {
  constexpr int K = 2048, N = 2048;
  __shared__ u16 sa[128][32];
  __shared__ u16 sb[128][32];
  int n0 = blockIdx.x * 128;
  int m0 = blockIdx.y * 128;
  int t = threadIdx.x;
  int lane = t & 63, w = t >> 6;
  int wm = (w >> 1) * 64, wn = (w & 1) * 64;
  int lr = lane & 15, lg = lane >> 4;
  int srow0 = w * 32 + (lane >> 2);
  int srow1 = srow0 + 16;
  int scol = (lane & 3) * 8;
  const u16* gA0 = &A[(size_t)(m0 + srow0) * K + scol];
  const u16* gA1 = &A[(size_t)(m0 + srow1) * K + scol];
  const u16* gB0 = &Bt[(size_t)(n0 + srow0) * K + scol];
  const u16* gB1 = &Bt[(size_t)(n0 + srow1) * K + scol];
  u16* lA0 = &sa[srow0][scol];
  u16* lA1 = &sa[srow1][scol];
  u16* lB0 = &sb[srow0][scol];
  u16* lB1 = &sb[srow1][scol];
  f32x4 acc[4][4] = {};
  for (int k0 = 0; k0 < K; k0 += 32) {
    __syncthreads();
    GLL16(gA0 + k0, lA0); GLL16(gA1 + k0, lA1);
    GLL16(gB0 + k0, lB0); GLL16(gB1 + k0, lB1);
    __syncthreads();
    s16x8 af[4], bf[4];
#pragma unroll
    for (int i = 0; i < 4; ++i) af[i] = *(const s16x8*)&sa[wm + i * 16 + lr][lg * 8];
#pragma unroll
    for (int i = 0; i < 4; ++i) bf[i] = *(const s16x8*)&sb[wn + i * 16 + lr][lg * 8];
#pragma unroll
    for (int mi = 0; mi < 4; ++mi)
#pragma unroll
      for (int ni = 0; ni < 4; ++ni)
        acc[mi][ni] = MFMA16(af[mi], bf[ni], acc[mi][ni], 0, 0, 0);
  }
#pragma unroll
  for (int mi = 0; mi < 4; ++mi)
#pragma unroll
    for (int ni = 0; ni < 4; ++ni)
#pragma unroll
      for (int r = 0; r < 4; ++r) {
        int m = m0 + wm + mi * 16 + lg * 4 + r;
        int n = n0 + wn + ni * 16 + lr;
        C[(size_t)m * N + n] = acc[mi][ni][r];
      }
}

// ---------- Flash attention (causal): no K/V LDS staging, no barriers ----------
// K and V^T fragments are loaded directly from global: the 8-element MFMA
// fragment is contiguous in memory for both (K along d, V^T along s), all 4
// waves of a block read identical K/V addresses (L1 broadcast), and all
// q-tiles of one bh land on one XCD (grid x=bh, 32%8==0) so the 1 MB K+V of
// each bh stays L2-resident (4 bh x 1 MB = 4 MB/XCD).
__global__ __launch_bounds__(256) void k_attn(const u16* __restrict__ q, const u16* __restrict__ k,
                                              const u16* __restrict__ vt, u16* __restrict__ y) {
  constexpr int S = 2048, HD = 128;
  __shared__ u16 pl[4][16][72];  // per-wave P (16 q x 64 kv)
  int bh = blockIdx.x;
  int qt = (gridDim.y - 1) - blockIdx.y;   // biggest q-tiles dispatched first (LPT)
  int q0 = qt * 64;
  int t = threadIdx.x, lane = t & 63, w = t >> 6;
  int lr = lane & 15, lg = lane >> 4;
  const size_t base = (size_t)bh * S * HD;
  const u16* kbh = k + base;
  const u16* vbh = vt + base;

  s16x8 aq[4];
  {
    size_t qrow = base + (size_t)(q0 + w * 16 + lr) * HD;
#pragma unroll
    for (int i = 0; i < 4; ++i) aq[i] = *(const s16x8*)&q[qrow + i * 32 + lg * 8];
  }
  f32x4 o[8] = {};
  float mrow[4] = {-INFINITY, -INFINITY, -INFINITY, -INFINITY};
  float lsum[4] = {};
  const float scale = 0.08838834764831845f;
  int kv_end = q0 + 64;
  for (int kv0 = 0; kv0 < kv_end; kv0 += 64) {
    // ---- QK^T: B-fragment (K) straight from global (contiguous along d) ----
    f32x4 sf[4] = {};
#pragma unroll
    for (int dstep = 0; dstep < 4; ++dstep)
#pragma unroll
      for (int nt = 0; nt < 4; ++nt) {
        s16x8 bk = *(const s16x8*)&kbh[(size_t)(kv0 + nt * 16 + lr) * HD + dstep * 32 + lg * 8];
        sf[nt] = MFMA16(aq[dstep], bk, sf[nt], 0, 0, 0);
      }
    // ---- online softmax ----
    int grow0 = q0 + w * 16 + lg * 4;
    float pmax[4] = {-INFINITY, -INFINITY, -INFINITY, -INFINITY};
#pragma unroll
    for (int nt = 0; nt < 4; ++nt) {
      int col = kv0 + nt * 16 + lr;
#pragma unroll
      for (int r = 0; r < 4; ++r) {
        float sv = sf[nt][r] * scale;
        if (col > grow0 + r) sv = -INFINITY;
        sf[nt][r] = sv;
        pmax[r] = fmaxf(pmax[r], sv);
      }
    }
#pragma unroll
    for (int r = 0; r < 4; ++r) {
#pragma unroll
      for (int off = 1; off < 16; off <<= 1) pmax[r] = fmaxf(pmax[r], __shfl_xor(pmax[r], off));
      float mn = fmaxf(mrow[r], pmax[r]);
      float alpha = __expf(mrow[r] - mn);
      mrow[r] = mn;
      float ps = 0.f;
#pragma unroll
      for (int nt = 0; nt < 4; ++nt) { float e = __expf(sf[nt][r] - mn); sf[nt][r] = e; ps += e; }
#pragma unroll
      for (int off = 1; off < 16; off <<= 1) ps += __shfl_xor(ps, off);
      lsum[r] = lsum[r] * alpha + ps;
#pragma unroll
      for (int dt = 0; dt < 8; ++dt) o[dt][r] *= alpha;
    }
    // ---- P -> bf16 via per-wave LDS (A-fragment relayout) ----
#pragma unroll
    for (int nt = 0; nt < 4; ++nt)
#pragma unroll
      for (int r = 0; r < 4; ++r)
        pl[w][lg * 4 + r][nt * 16 + lr] = f2b(sf[nt][r]);
    asm volatile("s_waitcnt lgkmcnt(0)" ::: "memory");
    __builtin_amdgcn_sched_barrier(0);
    s16x8 pa0 = *(const s16x8*)&pl[w][lr][lg * 8];
    s16x8 pa1 = *(const s16x8*)&pl[w][lr][32 + lg * 8];
    // ---- PV: B-fragment (V^T) straight from global (contiguous along s) ----
#pragma unroll
    for (int dt = 0; dt < 8; ++dt) {
      s16x8 bv0 = *(const s16x8*)&vbh[(size_t)(dt * 16 + lr) * S + kv0 + lg * 8];
      s16x8 bv1 = *(const s16x8*)&vbh[(size_t)(dt * 16 + lr) * S + kv0 + 32 + lg * 8];
      o[dt] = MFMA16(pa0, bv0, o[dt], 0, 0, 0);
      o[dt] = MFMA16(pa1, bv1, o[dt], 0, 0, 0);
    }
  }
  int b = bh >> 4, h = bh & 15;
#pragma unroll
  for (int dt = 0; dt < 8; ++dt)
#pragma unroll
    for (int r = 0; r < 4; ++r) {
      int srow = q0 + w * 16 + lg * 4 + r;
      float val = o[dt][r] / lsum[r];
      y[((size_t)(b * 2048 + srow)) * 2048 + h * 128 + dt * 16 + lr] = f2b(val);
    }
}

extern "C" void kernel_launch(void* const* d_in, const int* in_sizes, int n_in,
                              void* d_out, int out_size, void* d_ws, size_t ws_size,
                              hipStream_t stream) {
  const float* x    = (const float*)d_in[0];
  const float* wqkv = (const float*)d_in[1];
  const float* wo   = (const float*)d_in[2];
  float* out = (float*)d_out;
  char* ws = (char*)d_ws;
  u16* xb    = (u16*)(ws);                           // 16 MB: x bf16 (4096x2048)
  u16* wqkvt = (u16*)(ws + (size_t)(16)  * 1048576); // 24 MB: Wqkv^T (6144x2048)
  u16* wot   = (u16*)(ws + (size_t)(40)  * 1048576); //  8 MB: Wo^T (2048x2048)
  u16* qb    = (u16*)(ws + (size_t)(48)  * 1048576); // 16 MB: q (B,H,S,128)
  u16* kb    = (u16*)(ws + (size_t)(64)  * 1048576); // 16 MB: k
  u16* vb    = (u16*)(ws + (size_t)(80)  * 1048576); // 16 MB: v
  u16* vtb   = (u16*)(ws + (size_t)(96)  * 1048576); // 16 MB: v^T (B,H,128,S)
  u16* yb    = (u16*)(ws + (size_t)(112) * 1048576); // 16 MB: attn out (B,S,D)
  float2* trig = (float2*)(ws + (size_t)(128) * 1048576); // 1 MB

  k_cvt<<<8192, 256, 0, stream>>>(x, xb);
  k_tconv<<<dim3(96, 32), 256, 0, stream>>>(wqkv, wqkvt, 2048, 6144);
  k_tconv<<<dim3(32, 32), 256, 0, stream>>>(wo, wot, 2048, 2048);
  k_trig<<<512, 256, 0, stream>>>(trig);
  k_gemm_qkv<<<dim3(48, 32), 256, 0, stream>>>(xb, wqkvt, qb, kb, vb);
  k_rope<<<dim3(4096, 2), 256, 0, stream>>>(qb, kb, trig);
  k_trv<<<dim3(32, 2, 32), 256, 0, stream>>>(vb, vtb);
  k_attn<<<dim3(32, 32), 256, 0, stream>>>(qb, kb, vtb, yb);
  k_gemm_out<<<dim3(16, 32), 256, 0, stream>>>(yb, wot, out);
}

// Round 5
// 399.453 us; speedup vs baseline: 1.1360x; 1.1360x over previous
//
#include <hip/hip_runtime.h>
#include <hip/hip_bf16.h>

typedef __attribute__((ext_vector_type(4))) float f32x4;
typedef __attribute__((ext_vector_type(8))) short s16x8;
typedef unsigned short u16;
typedef unsigned int u32;

#define MFMA16 __builtin_amdgcn_mfma_f32_16x16x32_bf16

// global_load_lds: LDS dest is wave-uniform base + lane*16 (linear!), global src per-lane.
#define GLL16(g, l)                                                        \
  __builtin_amdgcn_global_load_lds(                                        \
      (const __attribute__((address_space(1))) void*)(g),                  \
      (__attribute__((address_space(3))) void*)(l), 16, 0, 0)

__device__ __forceinline__ u16 f2b(float f) {
  u32 x = __builtin_bit_cast(u32, f);
  u32 r = (x + 0x7fffu + ((x >> 16) & 1u)) >> 16;
  return (u16)r;
}
__device__ __forceinline__ float b2f(u16 u) {
  u32 x = ((u32)u) << 16;
  return __builtin_bit_cast(float, x);
}

// ---------- fp32 -> bf16 elementwise (x) ----------
__global__ __launch_bounds__(256) void k_cvt(const float* __restrict__ in, u16* __restrict__ out) {
  size_t i = ((size_t)blockIdx.x * 256 + threadIdx.x) * 4;
  float4 v = *(const float4*)(in + i);
  ushort4 o; o.x = f2b(v.x); o.y = f2b(v.y); o.z = f2b(v.z); o.w = f2b(v.w);
  *(ushort4*)(out + i) = o;
}

// ---------- transpose + convert: in (R x C) fp32 -> out (C x R) bf16 ----------
__global__ __launch_bounds__(256) void k_tconv(const float* __restrict__ in, u16* __restrict__ out,
                                               int R, int C) {
  __shared__ u16 tile[64][72];
  int c0 = blockIdx.x * 64, r0 = blockIdx.y * 64;
  int t = threadIdx.x;
#pragma unroll
  for (int p = 0; p < 4; ++p) {
    int idx = p * 1024 + t * 4;
    int row = idx >> 6, col = idx & 63;
    float4 v = *(const float4*)&in[(size_t)(r0 + row) * C + c0 + col];
    tile[row][col]     = f2b(v.x);
    tile[row][col + 1] = f2b(v.y);
    tile[row][col + 2] = f2b(v.z);
    tile[row][col + 3] = f2b(v.w);
  }
  __syncthreads();
#pragma unroll
  for (int p = 0; p < 4; ++p) {
    int idx = p * 1024 + t * 4;
    int row = idx >> 6, col = idx & 63;   // row: c-dim, col: r-dim
    ushort4 o;
    o.x = tile[col][row]; o.y = tile[col + 1][row];
    o.z = tile[col + 2][row]; o.w = tile[col + 3][row];
    *(ushort4*)&out[(size_t)(c0 + row) * R + r0 + col] = o;
  }
}

// ---------- bf16 transpose per (b,h): (2048 s x 128 d) -> (128 d x 2048 s) ----------
__global__ __launch_bounds__(256) void k_trv(const u16* __restrict__ v, u16* __restrict__ vt) {
  __shared__ u16 tile[64][72];
  int bh = blockIdx.z;
  int s0 = blockIdx.x * 64, d0 = blockIdx.y * 64;
  const u16* src = v + (size_t)bh * 2048 * 128;
  u16* dst = vt + (size_t)bh * 2048 * 128;
  int t = threadIdx.x;
#pragma unroll
  for (int p = 0; p < 4; ++p) {
    int idx = p * 1024 + t * 4;
    int row = idx >> 6, col = idx & 63;
    ushort4 x = *(const ushort4*)&src[(size_t)(s0 + row) * 128 + d0 + col];
    tile[row][col] = x.x; tile[row][col + 1] = x.y;
    tile[row][col + 2] = x.z; tile[row][col + 3] = x.w;
  }
  __syncthreads();
#pragma unroll
  for (int p = 0; p < 4; ++p) {
    int idx = p * 1024 + t * 4;
    int row = idx >> 6, col = idx & 63;   // row: d-local, col: s-local
    ushort4 o;
    o.x = tile[col][row]; o.y = tile[col + 1][row];
    o.z = tile[col + 2][row]; o.w = tile[col + 3][row];
    *(ushort4*)&dst[(size_t)(d0 + row) * 2048 + s0 + col] = o;
  }
}

// ---------- RoPE trig table ----------
__global__ __launch_bounds__(256) void k_trig(float2* __restrict__ tab) {
  int t = blockIdx.x * 256 + threadIdx.x;      // 2048*64
  int s = t >> 6, i = t & 63;
  float inv = expf(-(float)i * (9.210340371976184f / 64.f)); // ln(10000)
  float a = (float)s * inv;
  float sn, cs;
  sincosf(a, &sn, &cs);
  tab[t] = make_float2(cs, sn);
}

// ---------- RoPE in-place on q (y=0) / k (y=1), (B*H, S, 128) bf16 ----------
__global__ __launch_bounds__(256) void k_rope(u16* __restrict__ q, u16* __restrict__ k,
                                              const float2* __restrict__ tab) {
  u16* ptr = blockIdx.y ? k : q;
  size_t tid = (size_t)blockIdx.x * 256 + threadIdx.x;  // 32*2048*16
  int g = (int)(tid & 15);
  int s = (int)((tid >> 4) & 2047);
  int bh = (int)(tid >> 15);
  size_t base = ((size_t)bh * 2048 + s) * 128 + (size_t)g * 8;
  uint4 dv = *(const uint4*)(ptr + base);
  u16* pu = (u16*)&dv;
  const float2* tb = &tab[s * 64 + g * 4];
#pragma unroll
  for (int j = 0; j < 4; ++j) {
    float xe = b2f(pu[2 * j]), xo = b2f(pu[2 * j + 1]);
    float c = tb[j].x, sn = tb[j].y;
    pu[2 * j]     = f2b(xe * c - xo * sn);
    pu[2 * j + 1] = f2b(xe * sn + xo * c);
  }
  *(uint4*)(ptr + base) = dv;
}

// ---------- GEMM1 (m97 structure): qkv = xb @ WqkvT^T, scatter into q/k/v (B,H,S,128) ----------
__global__ __launch_bounds__(256) void k_gemm_qkv(const u16* __restrict__ A, const u16* __restrict__ Bt,
                                                  u16* __restrict__ qo, u16* __restrict__ ko,
                                                  u16* __restrict__ vo) {
  constexpr int K = 2048;
  __shared__ u16 sa[128][32];   // linear — required by global_load_lds
  __shared__ u16 sb[128][32];
  int n0 = blockIdx.x * 128;
  int m0 = blockIdx.y * 128;
  int t = threadIdx.x;
  int lane = t & 63, w = t >> 6;
  int wm = (w >> 1) * 64, wn = (w & 1) * 64;
  int lr = lane & 15, lg = lane >> 4;
  int srow0 = w * 32 + (lane >> 2);       // slot 2w
  int srow1 = srow0 + 16;                 // slot 2w+1
  int scol = (lane & 3) * 8;
  const u16* gA0 = &A[(size_t)(m0 + srow0) * K + scol];
  const u16* gA1 = &A[(size_t)(m0 + srow1) * K + scol];
  const u16* gB0 = &Bt[(size_t)(n0 + srow0) * K + scol];
  const u16* gB1 = &Bt[(size_t)(n0 + srow1) * K + scol];
  u16* lA0 = &sa[srow0][scol];
  u16* lA1 = &sa[srow1][scol];
  u16* lB0 = &sb[srow0][scol];
  u16* lB1 = &sb[srow1][scol];
  f32x4 acc[4][4] = {};
  for (int k0 = 0; k0 < K; k0 += 32) {
    __syncthreads();
    GLL16(gA0 + k0, lA0); GLL16(gA1 + k0, lA1);
    GLL16(gB0 + k0, lB0); GLL16(gB1 + k0, lB1);
    __syncthreads();
    s16x8 af[4], bf[4];
#pragma unroll
    for (int i = 0; i < 4; ++i) af[i] = *(const s16x8*)&sa[wm + i * 16 + lr][lg * 8];
#pragma unroll
    for (int i = 0; i < 4; ++i) bf[i] = *(const s16x8*)&sb[wn + i * 16 + lr][lg * 8];
#pragma unroll
    for (int mi = 0; mi < 4; ++mi)
#pragma unroll
      for (int ni = 0; ni < 4; ++ni)
        acc[mi][ni] = MFMA16(af[mi], bf[ni], acc[mi][ni], 0, 0, 0);
  }
  int which = blockIdx.x >> 4;
  int h = blockIdx.x & 15;
  u16* dst = which == 0 ? qo : (which == 1 ? ko : vo);
#pragma unroll
  for (int mi = 0; mi < 4; ++mi)
#pragma unroll
    for (int ni = 0; ni < 4; ++ni)
#pragma unroll
      for (int r = 0; r < 4; ++r) {
        int m = m0 + wm + mi * 16 + lg * 4 + r;
        int d = wn + ni * 16 + lr;
        int b = m >> 11, s = m & 2047;
        dst[(((size_t)b * 16 + h) * 2048 + s) * 128 + d] = f2b(acc[mi][ni][r]);
      }
}

// ---------- GEMM2 (m97 structure): out(fp32) = y(bf16) @ WoT^T ----------
__global__ __launch_bounds__(256) void k_gemm_out(const u16* __restrict__ A, const u16* __restrict__ Bt,
                                                  float* __restrict__ C) {
  constexpr int K = 2048, N = 2048;
  __shared__ u16 sa[128][32];
  __shared__ u16 sb[128][32];
  int n0 = blockIdx.x * 128;
  int m0 = blockIdx.y * 128;
  int t = threadIdx.x;
  int lane = t & 63, w = t >> 6;
  int wm = (w >> 1) * 64, wn = (w & 1) * 64;
  int lr = lane & 15, lg = lane >> 4;
  int srow0 = w * 32 + (lane >> 2);
  int srow1 = srow0 + 16;
  int scol = (lane & 3) * 8;
  const u16* gA0 = &A[(size_t)(m0 + srow0) * K + scol];
  const u16* gA1 = &A[(size_t)(m0 + srow1) * K + scol];
  const u16* gB0 = &Bt[(size_t)(n0 + srow0) * K + scol];
  const u16* gB1 = &Bt[(size_t)(n0 + srow1) * K + scol];
  u16* lA0 = &sa[srow0][scol];
  u16* lA1 = &sa[srow1][scol];
  u16* lB0 = &sb[srow0][scol];
  u16* lB1 = &sb[srow1][scol];
  f32x4 acc[4][4] = {};
  for (int k0 = 0; k0 < K; k0 += 32) {
    __syncthreads();
    GLL16(gA0 + k0, lA0); GLL16(gA1 + k0, lA1);
    GLL16(gB0 + k0, lB0); GLL16(gB1 + k0, lB1);
    __syncthreads();
    s16x8 af[4], bf[4];
#pragma unroll
    for (int i = 0; i < 4; ++i) af[i] = *(const s16x8*)&sa[wm + i * 16 + lr][lg * 8];
#pragma unroll
    for (int i = 0; i < 4; ++i) bf[i] = *(const s16x8*)&sb[wn + i * 16 + lr][lg * 8];
#pragma unroll
    for (int mi = 0; mi < 4; ++mi)
#pragma unroll
      for (int ni = 0; ni < 4; ++ni)
        acc[mi][ni] = MFMA16(af[mi], bf[ni], acc[mi][ni], 0, 0, 0);
  }
#pragma unroll
  for (int mi = 0; mi < 4; ++mi)
#pragma unroll
    for (int ni = 0; ni < 4; ++ni)
#pragma unroll
      for (int r = 0; r < 4; ++r) {
        int m = m0 + wm + mi * 16 + lg * 4 + r;
        int n = n0 + wn + ni * 16 + lr;
        C[(size_t)m * N + n] = acc[mi][ni][r];
      }
}

// ---------- Flash attention (causal): staged K/V + reg-prefetch (T14) + ILP softmax + setprio ----------
__global__ __launch_bounds__(256) void k_attn(const u16* __restrict__ q, const u16* __restrict__ k,
                                              const u16* __restrict__ vt, u16* __restrict__ y) {
  constexpr int S = 2048, HD = 128;
  __shared__ u16 kt[64][136];    // kv x d (padded)
  __shared__ u16 vtl[128][72];   // d x kv (padded)
  __shared__ u16 pl[4][16][72];  // per-wave P (16 q x 64 kv)
  int bh = blockIdx.x;
  int qt = (gridDim.y - 1) - blockIdx.y;   // biggest q-tiles dispatched first (LPT)
  int q0 = qt * 64;
  int t = threadIdx.x, lane = t & 63, w = t >> 6;
  int lr = lane & 15, lg = lane >> 4;
  const size_t base = (size_t)bh * S * HD;
  const u16* kbh = k + base;
  const u16* vbh = vt + base;

  s16x8 aq[4];
  {
    size_t qrow = base + (size_t)(q0 + w * 16 + lr) * HD;
#pragma unroll
    for (int i = 0; i < 4; ++i) aq[i] = *(const s16x8*)&q[qrow + i * 32 + lg * 8];
  }
  f32x4 o[8] = {};
  float mrow[4] = {-INFINITY, -INFINITY, -INFINITY, -INFINITY};
  float lsum[4] = {};
  const float scale = 0.08838834764831845f;
  int kv_end = q0 + 64;

  // prologue: prefetch tile 0 into regs
  uint4 pk[4], pv[4];
#pragma unroll
  for (int p = 0; p < 4; ++p) {
    int idx = p * 256 + t;
    pk[p] = *(const uint4*)&kbh[(size_t)(idx >> 4) * HD + (idx & 15) * 8];
    pv[p] = *(const uint4*)&vbh[(size_t)(idx >> 3) * S + (idx & 7) * 8];
  }
  for (int kv0 = 0; kv0 < kv_end; kv0 += 64) {
    __syncthreads();                // prior iter's LDS reads done
#pragma unroll
    for (int p = 0; p < 4; ++p) {   // commit staged regs -> LDS
      int idx = p * 256 + t;
      *(uint4*)&kt[idx >> 4][(idx & 15) * 8] = pk[p];
      *(uint4*)&vtl[idx >> 3][(idx & 7) * 8] = pv[p];
    }
    __syncthreads();
    if (kv0 + 64 < kv_end) {        // T14: issue next-tile loads; latency hides under compute
      int kn = kv0 + 64;
#pragma unroll
      for (int p = 0; p < 4; ++p) {
        int idx = p * 256 + t;
        pk[p] = *(const uint4*)&kbh[(size_t)(kn + (idx >> 4)) * HD + (idx & 15) * 8];
        pv[p] = *(const uint4*)&vbh[(size_t)(idx >> 3) * S + kn + (idx & 7) * 8];
      }
    }
    // ---- QK^T ----
    f32x4 sf[4] = {};
    __builtin_amdgcn_s_setprio(1);
#pragma unroll
    for (int dstep = 0; dstep < 4; ++dstep)
#pragma unroll
      for (int nt = 0; nt < 4; ++nt) {
        s16x8 bk = *(const s16x8*)&kt[nt * 16 + lr][dstep * 32 + lg * 8];
        sf[nt] = MFMA16(aq[dstep], bk, sf[nt], 0, 0, 0);
      }
    __builtin_amdgcn_s_setprio(0);
    // ---- online softmax (stage-major reduces: 4 rows' chains interleaved) ----
    int grow0 = q0 + w * 16 + lg * 4;
    float pmax[4] = {-INFINITY, -INFINITY, -INFINITY, -INFINITY};
#pragma unroll
    for (int nt = 0; nt < 4; ++nt) {
      int col = kv0 + nt * 16 + lr;
#pragma unroll
      for (int r = 0; r < 4; ++r) {
        float sv = sf[nt][r] * scale;
        if (col > grow0 + r) sv = -INFINITY;
        sf[nt][r] = sv;
        pmax[r] = fmaxf(pmax[r], sv);
      }
    }
#pragma unroll
    for (int off = 1; off < 16; off <<= 1)
#pragma unroll
      for (int r = 0; r < 4; ++r) pmax[r] = fmaxf(pmax[r], __shfl_xor(pmax[r], off));
    float alpha[4], ps[4];
#pragma unroll
    for (int r = 0; r < 4; ++r) {
      float mn = fmaxf(mrow[r], pmax[r]);
      alpha[r] = __expf(mrow[r] - mn);
      mrow[r] = mn;
      ps[r] = 0.f;
#pragma unroll
      for (int nt = 0; nt < 4; ++nt) { float e = __expf(sf[nt][r] - mn); sf[nt][r] = e; ps[r] += e; }
    }
#pragma unroll
    for (int off = 1; off < 16; off <<= 1)
#pragma unroll
      for (int r = 0; r < 4; ++r) ps[r] += __shfl_xor(ps[r], off);
#pragma unroll
    for (int r = 0; r < 4; ++r) {
      lsum[r] = lsum[r] * alpha[r] + ps[r];
#pragma unroll
      for (int dt = 0; dt < 8; ++dt) o[dt][r] *= alpha[r];
    }
    // ---- P -> bf16 via per-wave LDS (A-fragment relayout) ----
#pragma unroll
    for (int nt = 0; nt < 4; ++nt)
#pragma unroll
      for (int r = 0; r < 4; ++r)
        pl[w][lg * 4 + r][nt * 16 + lr] = f2b(sf[nt][r]);
    asm volatile("s_waitcnt lgkmcnt(0)" ::: "memory");
    __builtin_amdgcn_sched_barrier(0);
    s16x8 pa0 = *(const s16x8*)&pl[w][lr][lg * 8];
    s16x8 pa1 = *(const s16x8*)&pl[w][lr][32 + lg * 8];
    // ---- PV ----
    __builtin_amdgcn_s_setprio(1);
#pragma unroll
    for (int dt = 0; dt < 8; ++dt) {
      s16x8 bv0 = *(const s16x8*)&vtl[dt * 16 + lr][lg * 8];
      s16x8 bv1 = *(const s16x8*)&vtl[dt * 16 + lr][32 + lg * 8];
      o[dt] = MFMA16(pa0, bv0, o[dt], 0, 0, 0);
      o[dt] = MFMA16(pa1, bv1, o[dt], 0, 0, 0);
    }
    __builtin_amdgcn_s_setprio(0);
  }
  int b = bh >> 4, h = bh & 15;
#pragma unroll
  for (int dt = 0; dt < 8; ++dt)
#pragma unroll
    for (int r = 0; r < 4; ++r) {
      int srow = q0 + w * 16 + lg * 4 + r;
      float val = o[dt][r] / lsum[r];
      y[((size_t)(b * 2048 + srow)) * 2048 + h * 128 + dt * 16 + lr] = f2b(val);
    }
}

extern "C" void kernel_launch(void* const* d_in, const int* in_sizes, int n_in,
                              void* d_out, int out_size, void* d_ws, size_t ws_size,
                              hipStream_t stream) {
  const float* x    = (const float*)d_in[0];
  const float* wqkv = (const float*)d_in[1];
  const float* wo   = (const float*)d_in[2];
  float* out = (float*)d_out;
  char* ws = (char*)d_ws;
  u16* xb    = (u16*)(ws);                           // 16 MB: x bf16 (4096x2048)
  u16* wqkvt = (u16*)(ws + (size_t)(16)  * 1048576); // 24 MB: Wqkv^T (6144x2048)
  u16* wot   = (u16*)(ws + (size_t)(40)  * 1048576); //  8 MB: Wo^T (2048x2048)
  u16* qb    = (u16*)(ws + (size_t)(48)  * 1048576); // 16 MB: q (B,H,S,128)
  u16* kb    = (u16*)(ws + (size_t)(64)  * 1048576); // 16 MB: k
  u16* vb    = (u16*)(ws + (size_t)(80)  * 1048576); // 16 MB: v
  u16* vtb   = (u16*)(ws + (size_t)(96)  * 1048576); // 16 MB: v^T (B,H,128,S)
  u16* yb    = (u16*)(ws + (size_t)(112) * 1048576); // 16 MB: attn out (B,S,D)
  float2* trig = (float2*)(ws + (size_t)(128) * 1048576); // 1 MB

  k_cvt<<<8192, 256, 0, stream>>>(x, xb);
  k_tconv<<<dim3(96, 32), 256, 0, stream>>>(wqkv, wqkvt, 2048, 6144);
  k_tconv<<<dim3(32, 32), 256, 0, stream>>>(wo, wot, 2048, 2048);
  k_trig<<<512, 256, 0, stream>>>(trig);
  k_gemm_qkv<<<dim3(48, 32), 256, 0, stream>>>(xb, wqkvt, qb, kb, vb);
  k_rope<<<dim3(4096, 2), 256, 0, stream>>>(qb, kb, trig);
  k_trv<<<dim3(32, 2, 32), 256, 0, stream>>>(vb, vtb);
  k_attn<<<dim3(32, 32), 256, 0, stream>>>(qb, kb, vtb, yb);
  k_gemm_out<<<dim3(16, 32), 256, 0, stream>>>(yb, wot, out);
}

// Round 6
// 299.581 us; speedup vs baseline: 1.5148x; 1.3334x over previous
//
#include <hip/hip_runtime.h>
#include <hip/hip_bf16.h>

typedef __attribute__((ext_vector_type(4))) float f32x4;
typedef __attribute__((ext_vector_type(8))) short s16x8;
typedef unsigned short u16;
typedef unsigned int u32;

#define MFMA16 __builtin_amdgcn_mfma_f32_16x16x32_bf16

// global_load_lds: LDS dest is wave-uniform base + lane*16 (linear!), global src per-lane.
#define GLL16(g, l)                                                        \
  __builtin_amdgcn_global_load_lds(                                        \
      (const __attribute__((address_space(1))) void*)(g),                  \
      (__attribute__((address_space(3))) void*)(l), 16, 0, 0)

__device__ __forceinline__ u16 f2b(float f) {
  u32 x = __builtin_bit_cast(u32, f);
  u32 r = (x + 0x7fffu + ((x >> 16) & 1u)) >> 16;
  return (u16)r;
}
__device__ __forceinline__ float b2f(u16 u) {
  u32 x = ((u32)u) << 16;
  return __builtin_bit_cast(float, x);
}

// ---------- fp32 -> bf16 elementwise (x) ----------
__global__ __launch_bounds__(256) void k_cvt(const float* __restrict__ in, u16* __restrict__ out) {
  size_t i = ((size_t)blockIdx.x * 256 + threadIdx.x) * 4;
  float4 v = *(const float4*)(in + i);
  ushort4 o; o.x = f2b(v.x); o.y = f2b(v.y); o.z = f2b(v.z); o.w = f2b(v.w);
  *(ushort4*)(out + i) = o;
}

// ---------- transpose + convert: in (R x C) fp32 -> out (C x R) bf16 ----------
__global__ __launch_bounds__(256) void k_tconv(const float* __restrict__ in, u16* __restrict__ out,
                                               int R, int C) {
  __shared__ u16 tile[64][72];
  int c0 = blockIdx.x * 64, r0 = blockIdx.y * 64;
  int t = threadIdx.x;
#pragma unroll
  for (int p = 0; p < 4; ++p) {
    int idx = p * 1024 + t * 4;
    int row = idx >> 6, col = idx & 63;
    float4 v = *(const float4*)&in[(size_t)(r0 + row) * C + c0 + col];
    tile[row][col]     = f2b(v.x);
    tile[row][col + 1] = f2b(v.y);
    tile[row][col + 2] = f2b(v.z);
    tile[row][col + 3] = f2b(v.w);
  }
  __syncthreads();
#pragma unroll
  for (int p = 0; p < 4; ++p) {
    int idx = p * 1024 + t * 4;
    int row = idx >> 6, col = idx & 63;   // row: c-dim, col: r-dim
    ushort4 o;
    o.x = tile[col][row]; o.y = tile[col + 1][row];
    o.z = tile[col + 2][row]; o.w = tile[col + 3][row];
    *(ushort4*)&out[(size_t)(c0 + row) * R + r0 + col] = o;
  }
}

// ---------- bf16 transpose per (b,h): (2048 s x 128 d) -> (128 d x 2048 s) ----------
__global__ __launch_bounds__(256) void k_trv(const u16* __restrict__ v, u16* __restrict__ vt) {
  __shared__ u16 tile[64][72];
  int bh = blockIdx.z;
  int s0 = blockIdx.x * 64, d0 = blockIdx.y * 64;
  const u16* src = v + (size_t)bh * 2048 * 128;
  u16* dst = vt + (size_t)bh * 2048 * 128;
  int t = threadIdx.x;
#pragma unroll
  for (int p = 0; p < 4; ++p) {
    int idx = p * 1024 + t * 4;
    int row = idx >> 6, col = idx & 63;
    ushort4 x = *(const ushort4*)&src[(size_t)(s0 + row) * 128 + d0 + col];
    tile[row][col] = x.x; tile[row][col + 1] = x.y;
    tile[row][col + 2] = x.z; tile[row][col + 3] = x.w;
  }
  __syncthreads();
#pragma unroll
  for (int p = 0; p < 4; ++p) {
    int idx = p * 1024 + t * 4;
    int row = idx >> 6, col = idx & 63;   // row: d-local, col: s-local
    ushort4 o;
    o.x = tile[col][row]; o.y = tile[col + 1][row];
    o.z = tile[col + 2][row]; o.w = tile[col + 3][row];
    *(ushort4*)&dst[(size_t)(d0 + row) * 2048 + s0 + col] = o;
  }
}

// ---------- RoPE trig table ----------
__global__ __launch_bounds__(256) void k_trig(float2* __restrict__ tab) {
  int t = blockIdx.x * 256 + threadIdx.x;      // 2048*64
  int s = t >> 6, i = t & 63;
  float inv = expf(-(float)i * (9.210340371976184f / 64.f)); // ln(10000)
  float a = (float)s * inv;
  float sn, cs;
  sincosf(a, &sn, &cs);
  tab[t] = make_float2(cs, sn);
}

// ---------- RoPE in-place on q (y=0) / k (y=1), (B*H, S, 128) bf16 ----------
__global__ __launch_bounds__(256) void k_rope(u16* __restrict__ q, u16* __restrict__ k,
                                              const float2* __restrict__ tab) {
  u16* ptr = blockIdx.y ? k : q;
  size_t tid = (size_t)blockIdx.x * 256 + threadIdx.x;  // 32*2048*16
  int g = (int)(tid & 15);
  int s = (int)((tid >> 4) & 2047);
  int bh = (int)(tid >> 15);
  size_t base = ((size_t)bh * 2048 + s) * 128 + (size_t)g * 8;
  uint4 dv = *(const uint4*)(ptr + base);
  u16* pu = (u16*)&dv;
  const float2* tb = &tab[s * 64 + g * 4];
#pragma unroll
  for (int j = 0; j < 4; ++j) {
    float xe = b2f(pu[2 * j]), xo = b2f(pu[2 * j + 1]);
    float c = tb[j].x, sn = tb[j].y;
    pu[2 * j]     = f2b(xe * c - xo * sn);
    pu[2 * j + 1] = f2b(xe * sn + xo * c);
  }
  *(uint4*)(ptr + base) = dv;
}

// ---------- GEMM1 (m97 structure): qkv = xb @ WqkvT^T, scatter into q/k/v (B,H,S,128) ----------
__global__ __launch_bounds__(256) void k_gemm_qkv(const u16* __restrict__ A, const u16* __restrict__ Bt,
                                                  u16* __restrict__ qo, u16* __restrict__ ko,
                                                  u16* __restrict__ vo) {
  constexpr int K = 2048;
  __shared__ u16 sa[128][32];   // linear — required by global_load_lds
  __shared__ u16 sb[128][32];
  int n0 = blockIdx.x * 128;
  int m0 = blockIdx.y * 128;
  int t = threadIdx.x;
  int lane = t & 63, w = t >> 6;
  int wm = (w >> 1) * 64, wn = (w & 1) * 64;
  int lr = lane & 15, lg = lane >> 4;
  int srow0 = w * 32 + (lane >> 2);       // slot 2w
  int srow1 = srow0 + 16;                 // slot 2w+1
  int scol = (lane & 3) * 8;
  const u16* gA0 = &A[(size_t)(m0 + srow0) * K + scol];
  const u16* gA1 = &A[(size_t)(m0 + srow1) * K + scol];
  const u16* gB0 = &Bt[(size_t)(n0 + srow0) * K + scol];
  const u16* gB1 = &Bt[(size_t)(n0 + srow1) * K + scol];
  u16* lA0 = &sa[srow0][scol];
  u16* lA1 = &sa[srow1][scol];
  u16* lB0 = &sb[srow0][scol];
  u16* lB1 = &sb[srow1][scol];
  f32x4 acc[4][4] = {};
  for (int k0 = 0; k0 < K; k0 += 32) {
    __syncthreads();
    GLL16(gA0 + k0, lA0); GLL16(gA1 + k0, lA1);
    GLL16(gB0 + k0, lB0); GLL16(gB1 + k0, lB1);
    __syncthreads();
    s16x8 af[4], bf[4];
#pragma unroll
    for (int i = 0; i < 4; ++i) af[i] = *(const s16x8*)&sa[wm + i * 16 + lr][lg * 8];
#pragma unroll
    for (int i = 0; i < 4; ++i) bf[i] = *(const s16x8*)&sb[wn + i * 16 + lr][lg * 8];
#pragma unroll
    for (int mi = 0; mi < 4; ++mi)
#pragma unroll
      for (int ni = 0; ni < 4; ++ni)
        acc[mi][ni] = MFMA16(af[mi], bf[ni], acc[mi][ni], 0, 0, 0);
  }
  int which = blockIdx.x >> 4;
  int h = blockIdx.x & 15;
  u16* dst = which == 0 ? qo : (which == 1 ? ko : vo);
#pragma unroll
  for (int mi = 0; mi < 4; ++mi)
#pragma unroll
    for (int ni = 0; ni < 4; ++ni)
#pragma unroll
      for (int r = 0; r < 4; ++r) {
        int m = m0 + wm + mi * 16 + lg * 4 + r;
        int d = wn + ni * 16 + lr;
        int b = m >> 11, s = m & 2047;
        dst[(((size_t)b * 16 + h) * 2048 + s) * 128 + d] = f2b(acc[mi][ni][r]);
      }
}

// ---------- GEMM2 (m97 structure): out(fp32) = y(bf16) @ WoT^T ----------
__global__ __launch_bounds__(256) void k_gemm_out(const u16* __restrict__ A, const u16* __restrict__ Bt,
                                                  float* __restrict__ C) {
  constexpr int K = 2048, N = 2048;
  __shared__ u16 sa[128][32];
  __shared__ u16 sb[128][32];
  int n0 = blockIdx.x * 128;
  int m0 = blockIdx.y * 128;
  int t = threadIdx.x;
  int lane = t & 63, w = t >> 6;
  int wm = (w >> 1) * 64, wn = (w & 1) * 64;
  int lr = lane & 15, lg = lane >> 4;
  int srow0 = w * 32 + (lane >> 2);
  int srow1 = srow0 + 16;
  int scol = (lane & 3) * 8;
  const u16* gA0 = &A[(size_t)(m0 + srow0) * K + scol];
  const u16* gA1 = &A[(size_t)(m0 + srow1) * K + scol];
  const u16* gB0 = &Bt[(size_t)(n0 + srow0) * K + scol];
  const u16* gB1 = &Bt[(size_t)(n0 + srow1) * K + scol];
  u16* lA0 = &sa[srow0][scol];
  u16* lA1 = &sa[srow1][scol];
  u16* lB0 = &sb[srow0][scol];
  u16* lB1 = &sb[srow1][scol];
  f32x4 acc[4][4] = {};
  for (int k0 = 0; k0 < K; k0 += 32) {
    __syncthreads();
    GLL16(gA0 + k0, lA0); GLL16(gA1 + k0, lA1);
    GLL16(gB0 + k0, lB0); GLL16(gB1 + k0, lB1);
    __syncthreads();
    s16x8 af[4], bf[4];
#pragma unroll
    for (int i = 0; i < 4; ++i) af[i] = *(const s16x8*)&sa[wm + i * 16 + lr][lg * 8];
#pragma unroll
    for (int i = 0; i < 4; ++i) bf[i] = *(const s16x8*)&sb[wn + i * 16 + lr][lg * 8];
#pragma unroll
    for (int mi = 0; mi < 4; ++mi)
#pragma unroll
      for (int ni = 0; ni < 4; ++ni)
        acc[mi][ni] = MFMA16(af[mi], bf[ni], acc[mi][ni], 0, 0, 0);
  }
#pragma unroll
  for (int mi = 0; mi < 4; ++mi)
#pragma unroll
    for (int ni = 0; ni < 4; ++ni)
#pragma unroll
      for (int r = 0; r < 4; ++r) {
        int m = m0 + wm + mi * 16 + lg * 4 + r;
        int n = n0 + wn + ni * 16 + lr;
        C[(size_t)m * N + n] = acc[mi][ni][r];
      }
}

// ---------- Flash attention (causal): GLL double-buffered K/V staging ----------
// One barrier per KV-tile: __syncthreads()'s vmcnt(0) drain = the wait for the
// GLLs issued last iteration; stage of tile t+1 overlaps compute of tile t.
// Linear LDS (GLL requirement) + XOR swizzle (rule #21): inverse-swizzled
// global SOURCE + same XOR on READ, byte ^= (row&7)<<4 (involution).
__global__ __launch_bounds__(256) void k_attn(const u16* __restrict__ q, const u16* __restrict__ k,
                                              const u16* __restrict__ vt, u16* __restrict__ y) {
  constexpr int S = 2048, HD = 128;
  __shared__ u16 kt[2][64][128];   // 2 x 16 KB (kv x d), linear
  __shared__ u16 vtl[2][128][64];  // 2 x 16 KB (d x kv), linear
  __shared__ u16 pl[4][16][72];    // per-wave P (16 q x 64 kv)
  int bh = blockIdx.x;
  int qt = (gridDim.y - 1) - blockIdx.y;   // biggest q-tiles dispatched first (LPT)
  int q0 = qt * 64;
  int t = threadIdx.x, lane = t & 63, w = t >> 6;
  int lr = lane & 15, lg = lane >> 4;
  const size_t base = (size_t)bh * S * HD;
  const u16* kbh = k + base;
  const u16* vbh = vt + base;

  // staging geometry (per wave: 4 GLL for K, 4 for V; each GLL = 1 KB linear)
  int kr_l = ((w * 4) << 2) + (lane >> 4);          // K row for instr i=0 (add 4*i)
  int kcb_base = (lane & 15) << 4;                  // linear byte col in K row
  int vr_l = ((w * 4) << 3) + (lane >> 3);          // V row for instr i=0 (add 8*i)
  int vcb_base = (lane & 7) << 4;                   // linear byte col in V row

  s16x8 aq[4];
  {
    size_t qrow = base + (size_t)(q0 + w * 16 + lr) * HD;
#pragma unroll
    for (int i = 0; i < 4; ++i) aq[i] = *(const s16x8*)&q[qrow + i * 32 + lg * 8];
  }
  f32x4 o[8] = {};
  float mrow[4] = {-INFINITY, -INFINITY, -INFINITY, -INFINITY};
  float lsum[4] = {};
  const float scale = 0.08838834764831845f;
  int kv_end = q0 + 64;

#define STAGE_KV(buf, kv)                                                             \
  {                                                                                   \
    _Pragma("unroll")                                                                 \
    for (int i = 0; i < 4; ++i) {                                                     \
      int kr = kr_l + 4 * i;                                                          \
      int kcb = kcb_base ^ ((kr & 7) << 4);                                           \
      GLL16((const char*)(kbh + (size_t)((kv) + kr) * HD) + kcb,                      \
            (char*)&kt[buf][0][0] + ((w * 4 + i) << 10) + (lane << 4));               \
      int vr = vr_l + 8 * i;                                                          \
      int vcb = vcb_base ^ ((vr & 7) << 4);                                           \
      GLL16((const char*)(vbh + (size_t)vr * S + (kv)) + vcb,                         \
            (char*)&vtl[buf][0][0] + ((w * 4 + i) << 10) + (lane << 4));              \
    }                                                                                 \
  }

  STAGE_KV(0, 0);                 // prologue: stage tile 0
  int cur = 0;
  for (int kv0 = 0; kv0 < kv_end; kv0 += 64) {
    __syncthreads();              // vmcnt(0) drain => buf[cur] staged; all waves done reading buf[cur^1]
    if (kv0 + 64 < kv_end) STAGE_KV(cur ^ 1, kv0 + 64);   // overlaps with this tile's compute
    // ---- QK^T (swizzled K reads) ----
    f32x4 sf[4] = {};
    int swz = (lr & 7) << 4;
    __builtin_amdgcn_s_setprio(1);
#pragma unroll
    for (int dstep = 0; dstep < 4; ++dstep)
#pragma unroll
      for (int nt = 0; nt < 4; ++nt) {
        int cb = ((dstep << 6) + (lg << 4)) ^ swz;
        s16x8 bk = *(const s16x8*)((const char*)&kt[cur][nt * 16 + lr][0] + cb);
        sf[nt] = MFMA16(aq[dstep], bk, sf[nt], 0, 0, 0);
      }
    __builtin_amdgcn_s_setprio(0);
    // ---- online softmax (stage-major reduces: 4 rows' chains interleaved) ----
    int grow0 = q0 + w * 16 + lg * 4;
    float pmax[4] = {-INFINITY, -INFINITY, -INFINITY, -INFINITY};
#pragma unroll
    for (int nt = 0; nt < 4; ++nt) {
      int col = kv0 + nt * 16 + lr;
#pragma unroll
      for (int r = 0; r < 4; ++r) {
        float sv = sf[nt][r] * scale;
        if (col > grow0 + r) sv = -INFINITY;
        sf[nt][r] = sv;
        pmax[r] = fmaxf(pmax[r], sv);
      }
    }
#pragma unroll
    for (int off = 1; off < 16; off <<= 1)
#pragma unroll
      for (int r = 0; r < 4; ++r) pmax[r] = fmaxf(pmax[r], __shfl_xor(pmax[r], off));
    float alpha[4], ps[4];
#pragma unroll
    for (int r = 0; r < 4; ++r) {
      float mn = fmaxf(mrow[r], pmax[r]);
      alpha[r] = __expf(mrow[r] - mn);
      mrow[r] = mn;
      ps[r] = 0.f;
#pragma unroll
      for (int nt = 0; nt < 4; ++nt) { float e = __expf(sf[nt][r] - mn); sf[nt][r] = e; ps[r] += e; }
    }
#pragma unroll
    for (int off = 1; off < 16; off <<= 1)
#pragma unroll
      for (int r = 0; r < 4; ++r) ps[r] += __shfl_xor(ps[r], off);
#pragma unroll
    for (int r = 0; r < 4; ++r) {
      lsum[r] = lsum[r] * alpha[r] + ps[r];
#pragma unroll
      for (int dt = 0; dt < 8; ++dt) o[dt][r] *= alpha[r];
    }
    // ---- P -> bf16 via per-wave LDS (A-fragment relayout) ----
#pragma unroll
    for (int nt = 0; nt < 4; ++nt)
#pragma unroll
      for (int r = 0; r < 4; ++r)
        pl[w][lg * 4 + r][nt * 16 + lr] = f2b(sf[nt][r]);
    asm volatile("s_waitcnt lgkmcnt(0)" ::: "memory");
    __builtin_amdgcn_sched_barrier(0);
    s16x8 pa0 = *(const s16x8*)&pl[w][lr][lg * 8];
    s16x8 pa1 = *(const s16x8*)&pl[w][lr][32 + lg * 8];
    // ---- PV (swizzled V reads) ----
    __builtin_amdgcn_s_setprio(1);
#pragma unroll
    for (int dt = 0; dt < 8; ++dt) {
      int cb0 = (lg << 4) ^ swz;
      int cb1 = (64 + (lg << 4)) ^ swz;
      s16x8 bv0 = *(const s16x8*)((const char*)&vtl[cur][dt * 16 + lr][0] + cb0);
      s16x8 bv1 = *(const s16x8*)((const char*)&vtl[cur][dt * 16 + lr][0] + cb1);
      o[dt] = MFMA16(pa0, bv0, o[dt], 0, 0, 0);
      o[dt] = MFMA16(pa1, bv1, o[dt], 0, 0, 0);
    }
    __builtin_amdgcn_s_setprio(0);
    cur ^= 1;
  }
#undef STAGE_KV
  int b = bh >> 4, h = bh & 15;
#pragma unroll
  for (int dt = 0; dt < 8; ++dt)
#pragma unroll
    for (int r = 0; r < 4; ++r) {
      int srow = q0 + w * 16 + lg * 4 + r;
      float val = o[dt][r] / lsum[r];
      y[((size_t)(b * 2048 + srow)) * 2048 + h * 128 + dt * 16 + lr] = f2b(val);
    }
}

extern "C" void kernel_launch(void* const* d_in, const int* in_sizes, int n_in,
                              void* d_out, int out_size, void* d_ws, size_t ws_size,
                              hipStream_t stream) {
  const float* x    = (const float*)d_in[0];
  const float* wqkv = (const float*)d_in[1];
  const float* wo   = (const float*)d_in[2];
  float* out = (float*)d_out;
  char* ws = (char*)d_ws;
  u16* xb    = (u16*)(ws);                           // 16 MB: x bf16 (4096x2048)
  u16* wqkvt = (u16*)(ws + (size_t)(16)  * 1048576); // 24 MB: Wqkv^T (6144x2048)
  u16* wot   = (u16*)(ws + (size_t)(40)  * 1048576); //  8 MB: Wo^T (2048x2048)
  u16* qb    = (u16*)(ws + (size_t)(48)  * 1048576); // 16 MB: q (B,H,S,128)
  u16* kb    = (u16*)(ws + (size_t)(64)  * 1048576); // 16 MB: k
  u16* vb    = (u16*)(ws + (size_t)(80)  * 1048576); // 16 MB: v
  u16* vtb   = (u16*)(ws + (size_t)(96)  * 1048576); // 16 MB: v^T (B,H,128,S)
  u16* yb    = (u16*)(ws + (size_t)(112) * 1048576); // 16 MB: attn out (B,S,D)
  float2* trig = (float2*)(ws + (size_t)(128) * 1048576); // 1 MB

  k_cvt<<<8192, 256, 0, stream>>>(x, xb);
  k_tconv<<<dim3(96, 32), 256, 0, stream>>>(wqkv, wqkvt, 2048, 6144);
  k_tconv<<<dim3(32, 32), 256, 0, stream>>>(wo, wot, 2048, 2048);
  k_trig<<<512, 256, 0, stream>>>(trig);
  k_gemm_qkv<<<dim3(48, 32), 256, 0, stream>>>(xb, wqkvt, qb, kb, vb);
  k_rope<<<dim3(4096, 2), 256, 0, stream>>>(qb, kb, trig);
  k_trv<<<dim3(32, 2, 32), 256, 0, stream>>>(vb, vtb);
  k_attn<<<dim3(32, 32), 256, 0, stream>>>(qb, kb, vtb, yb);
  k_gemm_out<<<dim3(16, 32), 256, 0, stream>>>(yb, wot, out);
}